// Round 8
// baseline (107.625 us; speedup 1.0000x reference)
//
#include <hip/hip_runtime.h>

#define B_ 512
#define T_ 1024
#define N_ 64
#define NA_ 66
#define CH 8
#define LN2 0.69314718055994530942f

typedef __attribute__((ext_vector_type(8))) short short8;
typedef __attribute__((ext_vector_type(4))) float f32x4;

__device__ __forceinline__ unsigned short bf16_rne(float f) {
    unsigned u = __float_as_uint(f);
    u += 0x7fffu + ((u >> 16) & 1u);
    return (unsigned short)(u >> 16);
}
__device__ __forceinline__ int pack_pair(float lo, float hi) {
    return (int)(((unsigned)bf16_rne(hi) << 16) | (unsigned)bf16_rne(lo));
}
__device__ __forceinline__ float dpp_swap1(float v) {   // lane j <-> j^1 (quad_perm)
    return __int_as_float(__builtin_amdgcn_update_dpp(
        0, __float_as_int(v), 0xB1, 0xF, 0xF, true));
}

__global__ __launch_bounds__(128) void crf_fb(
    const int* __restrict__ y,      // [B,T]
    const float* __restrict__ P,    // [B,T,N]
    const int* __restrict__ lens,   // [B]
    const float* __restrict__ A,    // [NA,NA]
    float* __restrict__ out)        // [B]
{
    const int b = blockIdx.x;
    const int tid = threadIdx.x;
    const int wv = tid >> 6;        // wave 0: forward alpha; wave 1: backward beta
    const int j = tid & 63;         // lane == state/column index
    const int g = j >> 4;
    const int m = j & 15;
    const long pbase = (long)b * (T_ * N_);
    const int yb = b * T_;
    const int len = lens[b];        // in [T/2, T]
    const int tsplit = (len - 1) >> 1;
    const int nsteps = wv ? (len - 1 - tsplit) : tsplit;   // each <= 512

    // B-fragments (k-map sigma(g,kh,e) = 32kh+8g+e): wave0 W=exp(Asub), wave1 W^T
    short8 Bf[4][2];
#pragma unroll
    for (int cb = 0; cb < 4; ++cb) {
        const int col = 16 * cb + m;
#pragma unroll
        for (int kh = 0; kh < 2; ++kh) {
#pragma unroll
            for (int e = 0; e < 8; ++e) {
                const int r = 32 * kh + 8 * g + e;
                const float av = wv ? A[col * NA_ + r] : A[r * NA_ + col];
                Bf[cb][kh][e] = (short)bf16_rne(__expf(av));
            }
        }
    }

    // bpermute byte-addresses (loop-invariant): A-frag dword w needs the packed
    // pair (z[k0], z[k0+1]) with k0 = 32kh+8g+2w, held by even lane k0.
    const int ad0 = (8 * g + 0) << 2, ad1 = (8 * g + 2) << 2;
    const int ad2 = (8 * g + 4) << 2, ad3 = (8 * g + 6) << 2;
    const int ad4 = ad0 + 128, ad5 = ad1 + 128, ad6 = ad2 + 128, ad7 = ad3 + 128;

    __shared__ float zfin[2][N_];
    __shared__ float part[2];
    __shared__ int msh[2];

    // init: fwd z = exp(A[START,j] + P[0,j]); bwd w = exp(A[j,END])
    float zown = wv ? __expf(A[j * NA_ + (N_ + 1)])
                    : __expf(A[N_ * NA_ + j] + P[pbase + j]);
    int Mexp = 0;
    int zpk = pack_pair(zown, dpp_swap1(zown));

    // gather A-frags from packed z, run matvec, select own column
    auto matstep = [&](int zp, float& sel, float& c00) {
        union { int i[4]; short8 s; } u1, u2;
        u1.i[0] = __builtin_amdgcn_ds_bpermute(ad0, zp);
        u1.i[1] = __builtin_amdgcn_ds_bpermute(ad1, zp);
        u1.i[2] = __builtin_amdgcn_ds_bpermute(ad2, zp);
        u1.i[3] = __builtin_amdgcn_ds_bpermute(ad3, zp);
        u2.i[0] = __builtin_amdgcn_ds_bpermute(ad4, zp);
        u2.i[1] = __builtin_amdgcn_ds_bpermute(ad5, zp);
        u2.i[2] = __builtin_amdgcn_ds_bpermute(ad6, zp);
        u2.i[3] = __builtin_amdgcn_ds_bpermute(ad7, zp);
        f32x4 c0 = {0.f, 0.f, 0.f, 0.f};
        f32x4 c1 = {0.f, 0.f, 0.f, 0.f};
        f32x4 c2 = {0.f, 0.f, 0.f, 0.f};
        f32x4 c3 = {0.f, 0.f, 0.f, 0.f};
        c0 = __builtin_amdgcn_mfma_f32_16x16x32_bf16(u1.s, Bf[0][0], c0, 0, 0, 0);
        c0 = __builtin_amdgcn_mfma_f32_16x16x32_bf16(u2.s, Bf[0][1], c0, 0, 0, 0);
        c1 = __builtin_amdgcn_mfma_f32_16x16x32_bf16(u1.s, Bf[1][0], c1, 0, 0, 0);
        c1 = __builtin_amdgcn_mfma_f32_16x16x32_bf16(u2.s, Bf[1][1], c1, 0, 0, 0);
        c2 = __builtin_amdgcn_mfma_f32_16x16x32_bf16(u1.s, Bf[2][0], c2, 0, 0, 0);
        c2 = __builtin_amdgcn_mfma_f32_16x16x32_bf16(u2.s, Bf[2][1], c2, 0, 0, 0);
        c3 = __builtin_amdgcn_mfma_f32_16x16x32_bf16(u1.s, Bf[3][0], c3, 0, 0, 0);
        c3 = __builtin_amdgcn_mfma_f32_16x16x32_bf16(u2.s, Bf[3][1], c3, 0, 0, 0);
        const float c01 = (g & 1) ? c1[0] : c0[0];
        const float c23 = (g & 1) ? c3[0] : c2[0];
        sel = (g & 2) ? c23 : c01;
        c00 = c0[0];
    };

    // fwd: z' = sel(z*W) * ep * 2^-6 ; pack at end for next step
    auto stepF = [&](float praw, bool renorm) {
        float sel, c00;
        matstep(zpk, sel, c00);
        float zn;
        if (renorm) {
            const int sb = __builtin_amdgcn_readfirstlane(__float_as_int(c00));
            const int e0 = ((sb >> 23) & 0xff) - 127;
            zn = ldexpf(sel, -e0) * __expf(praw);
            Mexp += e0;
        } else {
            zn = sel * (__expf(praw) * 0.015625f);
            Mexp += 6;
        }
        zown = zn;
        zpk = pack_pair(zn, dpp_swap1(zn));
    };

    // bwd: w' = sel((w .* ep * 2^-6) * W^T) ; pack at start
    auto stepB = [&](float praw, bool renorm) {
        const float ws = renorm ? zown * __expf(praw)
                                : zown * (__expf(praw) * 0.015625f);
        zpk = pack_pair(ws, dpp_swap1(ws));
        float sel, c00;
        matstep(zpk, sel, c00);
        if (renorm) {
            const int sb = __builtin_amdgcn_readfirstlane(__float_as_int(c00));
            const int e0 = ((sb >> 23) & 0xff) - 127;
            sel = ldexpf(sel, -e0);
            Mexp += e0;
        } else {
            Mexp += 6;
        }
        zown = sel;
    };

    const int nchunks = nsteps / CH;
    const int rem = nsteps - nchunks * CH;
    float prA[CH], prB[CH];
    auto issue = [&](int k, float (&dst)[CH]) {
#pragma unroll
        for (int u = 0; u < CH; ++u) {
            const int i = k * CH + u;
            int t = wv ? (len - 1 - i) : (1 + i);
            t = t < 0 ? 0 : (t >= T_ ? T_ - 1 : t);   // clamp; overshoot unused
            dst[u] = P[pbase + (long)t * N_ + j];
        }
    };

    if (wv == 0) {
        auto runC = [&](float (&src)[CH]) {
#pragma unroll
            for (int u = 0; u < CH; ++u) stepF(src[u], u == 0);
        };
        auto runT = [&](float (&src)[CH], int tc) {
#pragma unroll
            for (int u = 0; u < CH; ++u)
                if (u < tc) stepF(src[u], u == 0);    // wave-uniform
        };
        issue(0, prA);
        int c = 0;
        for (; c + 1 < nchunks; c += 2) {
            issue(c + 1, prB); runC(prA);
            issue(c + 2, prA); runC(prB);
        }
        if (c < nchunks) { issue(c + 1, prB); runC(prA); runT(prB, rem); }
        else             { runT(prA, rem); }
    } else {
        auto runC = [&](float (&src)[CH]) {
#pragma unroll
            for (int u = 0; u < CH; ++u) stepB(src[u], u == 0);
        };
        auto runT = [&](float (&src)[CH], int tc) {
#pragma unroll
            for (int u = 0; u < CH; ++u)
                if (u < tc) stepB(src[u], u == 0);    // wave-uniform
        };
        issue(0, prA);
        int c = 0;
        for (; c + 1 < nchunks; c += 2) {
            issue(c + 1, prB); runC(prA);
            issue(c + 2, prA); runC(prB);
        }
        if (c < nchunks) { issue(c + 1, prB); runC(prA); runT(prB, rem); }
        else             { runT(prA, rem); }
    }

    zfin[wv][j] = zown;
    if (j == 0) msh[wv] = Mexp;

    // ---- score partials: wave0 emit, wave1 inner ----
    const int NK = T_ / 64;             // 16
    int yk[NK];
#pragma unroll
    for (int k = 0; k < NK; ++k)
        yk[k] = y[yb + j + 64 * k];
    float sc = 0.f;
    if (wv == 0) {
#pragma unroll
        for (int k = 0; k < NK; ++k) {
            const int t = j + 64 * k;
            sc += (t < len) ? P[pbase + (long)t * N_ + yk[k]] : 0.f;
        }
    } else {
        int carry = 0;
#pragma unroll
        for (int k = 0; k < NK; ++k) {
            const int t = j + 64 * k;
            int yp = __shfl_up(yk[k], 1, 64);
            if (j == 0) yp = carry;
            carry = __shfl(yk[k], 63, 64);
            sc += (t >= 1 && t < len) ? A[yp * NA_ + yk[k]] : 0.f;
        }
    }
#pragma unroll
    for (int off = 32; off >= 1; off >>= 1)
        sc += __shfl_xor(sc, off, 64);
    if (j == 0) part[wv] = sc;
    __syncthreads();

    // ---- combine: logZ = log(sum_j zF_j*zB_j) + (MexpF+MexpB)*ln2 ----
    if (wv == 0) {
        float send = zfin[0][j] * zfin[1][j];
#pragma unroll
        for (int off = 32; off >= 1; off >>= 1)
            send += __shfl_xor(send, off, 64);
        if (j == 0) {
            const float logZ = __logf(send) + (float)(msh[0] + msh[1]) * LN2;
            const int y0 = y[yb];
            const float start = A[N_ * NA_ + y0];
            const int ylast = y[yb + len - 1];
            const float endv = A[ylast * NA_ + (N_ + 1)];
            out[b] = logZ - (part[0] + part[1] + start + endv);
        }
    }
}

extern "C" void kernel_launch(void* const* d_in, const int* in_sizes, int n_in,
                              void* d_out, int out_size, void* d_ws, size_t ws_size,
                              hipStream_t stream) {
    const int* y = (const int*)d_in[0];
    const float* P = (const float*)d_in[1];
    const int* lens = (const int*)d_in[2];
    const float* A = (const float*)d_in[3];
    float* out = (float*)d_out;
    crf_fb<<<dim3(B_), dim3(128), 0, stream>>>(y, P, lens, A, out);
}

// Round 9
// 51.562 us; speedup vs baseline: 2.0873x; 2.0873x over previous
//
#include <hip/hip_runtime.h>

#define B_ 512
#define T_ 1024
#define N_ 64
#define NA_ 66
#define CH 8
#define K_ 8
#define BURN 8
#define LN2 0.69314718055994530942f

typedef __attribute__((ext_vector_type(8))) short short8;
typedef __attribute__((ext_vector_type(4))) float f32x4;

__device__ __forceinline__ unsigned short bf16_rne(float f) {
    unsigned u = __float_as_uint(f);
    u += 0x7fffu + ((u >> 16) & 1u);
    return (unsigned short)(u >> 16);
}

__global__ __launch_bounds__(512) void crf_seg(
    const int* __restrict__ y,      // [B,T]
    const float* __restrict__ P,    // [B,T,N]
    const int* __restrict__ lens,   // [B]
    const float* __restrict__ A,    // [NA,NA]
    float* __restrict__ out)        // [B]
{
    const int b = blockIdx.x;
    const int tid = threadIdx.x;
    const int s = tid >> 6;         // wave == segment index 0..7
    const int j = tid & 63;         // lane == state/column index
    const int g = j >> 4;
    const int m = j & 15;
    const long pbase = (long)b * (T_ * N_);
    const int yb = b * T_;
    const int len = lens[b];        // in [T/2, T]
    const int n = len - 1;          // total scan steps (511..1023)
    const int L = (n + K_ - 1) / K_;            // owned steps per segment
    const int t_last = min((s + 1) * L, n);     // last owned step
    const int burn = (s == 0) ? 0 : BURN;
    const int t0 = s * L + 1 - burn;            // first executed step (>=1)
    const int nsteps = t_last - t0 + 1;         // executed steps (>= 9)

    // B-fragments of W = exp(Asub), k-map sigma(kh,g,e) = 32kh+8g+e (proven r4-r7)
    short8 Bf[4][2];
#pragma unroll
    for (int cb = 0; cb < 4; ++cb) {
        const int col = 16 * cb + m;
#pragma unroll
        for (int kh = 0; kh < 2; ++kh) {
#pragma unroll
            for (int e = 0; e < 8; ++e) {
                const int r = 32 * kh + 8 * g + e;
                Bf[cb][kh][e] = (short)bf16_rne(__expf(A[r * NA_ + col]));
            }
        }
    }

    __shared__ __align__(16) unsigned short zl[K_][N_];   // per-wave z (bf16)
    __shared__ float gsh[K_];
    __shared__ float psh[K_];
    unsigned short* zw = zl[s];

    // init: segment 0 exact alpha_0; others uniform (burn-in eats the error)
    float zown = (s == 0) ? __expf(A[N_ * NA_ + j] + P[pbase + j]) : 1.0f;
    int Mexp = 0;
    short8 a1, a2;

    // r7-verbatim forward step: z' = sel(z*W) * ep * 2^-6  (direct renorm at u==0)
    auto step = [&](float praw, bool renorm) {
        const float ep = __expf(praw);                    // off-chain
        const float sc = renorm ? ep : ep * 0.015625f;    // exact 2^-6
        zw[j] = bf16_rne(zown);
        __builtin_memcpy(&a1, (const void*)(zw + 8 * g), 16);
        __builtin_memcpy(&a2, (const void*)(zw + 32 + 8 * g), 16);
        f32x4 c0 = {0.f, 0.f, 0.f, 0.f};
        f32x4 c1 = {0.f, 0.f, 0.f, 0.f};
        f32x4 c2 = {0.f, 0.f, 0.f, 0.f};
        f32x4 c3 = {0.f, 0.f, 0.f, 0.f};
        c0 = __builtin_amdgcn_mfma_f32_16x16x32_bf16(a1, Bf[0][0], c0, 0, 0, 0);
        c0 = __builtin_amdgcn_mfma_f32_16x16x32_bf16(a2, Bf[0][1], c0, 0, 0, 0);
        c1 = __builtin_amdgcn_mfma_f32_16x16x32_bf16(a1, Bf[1][0], c1, 0, 0, 0);
        c1 = __builtin_amdgcn_mfma_f32_16x16x32_bf16(a2, Bf[1][1], c1, 0, 0, 0);
        c2 = __builtin_amdgcn_mfma_f32_16x16x32_bf16(a1, Bf[2][0], c2, 0, 0, 0);
        c2 = __builtin_amdgcn_mfma_f32_16x16x32_bf16(a2, Bf[2][1], c2, 0, 0, 0);
        c3 = __builtin_amdgcn_mfma_f32_16x16x32_bf16(a1, Bf[3][0], c3, 0, 0, 0);
        c3 = __builtin_amdgcn_mfma_f32_16x16x32_bf16(a2, Bf[3][1], c3, 0, 0, 0);
        const float c01 = (g & 1) ? c1[0] : c0[0];
        const float c23 = (g & 1) ? c3[0] : c2[0];
        float sel = (g & 2) ? c23 : c01;                  // own column j of S
        if (renorm) {
            const int sb = __builtin_amdgcn_readfirstlane(__float_as_int(c0[0]));
            const int e0 = ((sb >> 23) & 0xff) - 127;
            sel = ldexpf(sel, -e0);
            Mexp += e0;
        } else {
            Mexp += 6;
        }
        zown = sel * sc;
    };

    auto wave_sum = [&](float v) {
#pragma unroll
        for (int off = 32; off >= 1; off >>= 1)
            v += __shfl_xor(v, off, 64);
        return v;
    };

    const int NC = (nsteps + CH - 1) / CH;    // >= 2 always (nsteps >= 9)
    float prA[CH], prB[CH];
    auto issue = [&](int k, float (&dst)[CH]) {
#pragma unroll
        for (int u = 0; u < CH; ++u) {
            int t = t0 + k * CH + u;
            t = t < T_ ? t : T_ - 1;          // clamp; overshoot values unused
            dst[u] = P[pbase + (long)t * N_ + j];
        }
    };
    auto runChunk = [&](float (&src)[CH], int cnt) {
#pragma unroll
        for (int u = 0; u < CH; ++u)
            if (u < cnt) step(src[u], u == 0);            // wave-uniform
    };

    // chunk 0 (== burn-in for s>0, BURN==CH), snapshot after
    issue(0, prA);
    issue(1, prB);
    runChunk(prA, nsteps < CH ? nsteps : CH);
    float nchk = 0.0f;
    if (s > 0)
        nchk = (float)Mexp * LN2 + __logf(wave_sum(zown));
    int k = 1;
    for (; k + 1 < NC; k += 2) {
        issue(k + 1, prA);
        runChunk(prB, CH);                                // chunk k (full)
        if (k + 2 < NC) issue(k + 2, prB);
        const int c2n = nsteps - (k + 1) * CH;
        runChunk(prA, c2n < CH ? c2n : CH);               // chunk k+1
    }
    if (k < NC)
        runChunk(prB, nsteps - k * CH);                   // last odd chunk

    // segment log-gain; owner (s==7 always) adds the END-vector direction term
    const float zsum = wave_sum(zown);
    float G = (float)Mexp * LN2 + __logf(zsum) - nchk;
    if (s == K_ - 1) {
        const float vs = wave_sum(zown * __expf(A[j * NA_ + (N_ + 1)]));
        G += __logf(vs) - __logf(zsum);
    }
    if (j == 0) gsh[s] = G;

    // ---- score partials: wave s covers t = j + 64*{2s, 2s+1} ----
    float sc = 0.0f;
#pragma unroll
    for (int kk = 0; kk < 2; ++kk) {
        const int t = j + 64 * (2 * s + kk);
        if (t < len) {
            const int yt = y[yb + t];
            sc += P[pbase + (long)t * N_ + yt];
            if (t >= 1) sc += A[y[yb + t - 1] * NA_ + yt];
        }
    }
    sc = wave_sum(sc);
    if (j == 0) psh[s] = sc;
    __syncthreads();

    if (tid == 0) {
        float Gs = 0.f, Ss = 0.f;
#pragma unroll
        for (int w = 0; w < K_; ++w) { Gs += gsh[w]; Ss += psh[w]; }
        const int y0 = y[yb];
        const int yl = y[yb + len - 1];
        Ss += A[N_ * NA_ + y0] + A[yl * NA_ + (N_ + 1)];
        out[b] = Gs - Ss;
    }
}

extern "C" void kernel_launch(void* const* d_in, const int* in_sizes, int n_in,
                              void* d_out, int out_size, void* d_ws, size_t ws_size,
                              hipStream_t stream) {
    const int* y = (const int*)d_in[0];
    const float* P = (const float*)d_in[1];
    const int* lens = (const int*)d_in[2];
    const float* A = (const float*)d_in[3];
    float* out = (float*)d_out;
    crf_seg<<<dim3(B_), dim3(512), 0, stream>>>(y, P, lens, A, out);
}

// Round 10
// 45.459 us; speedup vs baseline: 2.3675x; 1.1343x over previous
//
#include <hip/hip_runtime.h>
#include <hip/hip_bf16.h>

#define B_ 512
#define T_ 1024
#define N_ 64
#define NA_ 66
#define LN2 0.69314718055994530942f

typedef __attribute__((ext_vector_type(8))) short short8;
typedef __attribute__((ext_vector_type(4))) float f32x4;

__device__ __forceinline__ unsigned short bf16_rne(float f) {
    unsigned u = __float_as_uint(f);
    u += 0x7fffu + ((u >> 16) & 1u);
    return (unsigned short)(u >> 16);
}
__device__ __forceinline__ int pack2(float a, float b) {
    __hip_bfloat162 h = __float22bfloat162_rn(make_float2(a, b)); // x -> low
    int r; __builtin_memcpy(&r, &h, 4); return r;
}

__global__ __launch_bounds__(64) void crf_mc16(
    const int* __restrict__ y,      // [B,T]
    const float* __restrict__ P,    // [B,T,N]
    const int* __restrict__ lens,   // [B]
    const float* __restrict__ A,    // [NA,NA]
    float* __restrict__ out)        // [B]
{
    const int b = blockIdx.x;
    const int l = threadIdx.x;
    const int g = l >> 4;           // k-group / output row-group / chain group
    const int m = l & 15;           // A-row = chain (reads); C col-pos (outputs)
    const long pbase = (long)b * (T_ * N_);
    const int yb = b * T_;
    const int len = lens[b];        // in [512, 1024]
    const int n = len - 1;          // scan steps 511..1023
    const int L = (n + 15) >> 4;    // owned steps per chain (32..64)
    const int E = L + 8;            // executed lockstep steps
    const int Epad = (E + 3) & ~3;
    const int uendC0 = L - 1;       // chain 0 end capture
    const int uend15 = n - 15 * L + 7;  // chain 15 end capture
    const int ufin = L + 7;         // chains 1..14 end capture

    // B-frags: B1[q][e] = W[8g+e][4m+q]*2^-6, B2 rows 32+8g+e. W = exp(Asub).
    // Column permutation pi(q,m)=4m+q makes each lane's outputs contiguous in P.
    short8 B1[4], B2[4];
#pragma unroll
    for (int q = 0; q < 4; ++q) {
        const int col = 4 * m + q;
#pragma unroll
        for (int e = 0; e < 8; ++e) {
            B1[q][e] = (short)bf16_rne(__expf(A[(8 * g + e) * NA_ + col]) * 0.015625f);
            B2[q][e] = (short)bf16_rne(__expf(A[(32 + 8 * g + e) * NA_ + col]) * 0.015625f);
        }
    }

    __shared__ __align__(16) unsigned char zb[2048];   // z[16 chains][64] bf16, swizzled

    // LDS addressing: granule (8 cols) position XOR-swizzled by (chain&7)
    const int roff1 = m * 128 + 16 * (g ^ (m & 7));          // chain m, cols 8g..
    const int roff2 = m * 128 + 16 * ((g + 4) ^ (m & 7));    // chain m, cols 32+8g..
    int woff[4];
    int t0_[4];
#pragma unroll
    for (int dr = 0; dr < 4; ++dr) {
        const int i = 4 * g + dr;   // chain this lane writes / scales (reg dr)
        woff[dr] = i * 128 + 16 * ((m >> 1) ^ (i & 7)) + 8 * (m & 1);
        t0_[dr] = i ? (i * L - 7) : 1;   // 8 burn-in steps for chains >= 1
    }

    const float4* __restrict__ p4 = (const float4*)(P + pbase);

    // init z: chain 0 = exp(A[START,:]+P[0,:]) exact; chains 1..15 uniform 1
    {
        const float4 p0 = p4[m];
        float v0 = __expf(A[N_ * NA_ + 4 * m + 0] + p0.x);
        float v1 = __expf(A[N_ * NA_ + 4 * m + 1] + p0.y);
        float v2 = __expf(A[N_ * NA_ + 4 * m + 2] + p0.z);
        float v3 = __expf(A[N_ * NA_ + 4 * m + 3] + p0.w);
#pragma unroll
        for (int dr = 0; dr < 4; ++dr) {
            const bool c0 = (g == 0 && dr == 0);
            int2 wv;
            wv.x = pack2(c0 ? v0 : 1.0f, c0 ? v1 : 1.0f);
            wv.y = pack2(c0 ? v2 : 1.0f, c0 ? v3 : 1.0f);
            __builtin_memcpy(zb + woff[dr], &wv, 8);
        }
    }

    float4 rbuf[4][4];              // prefetch ring [slot][dr], distance 4
#pragma unroll
    for (int du = 0; du < 4; ++du)
#pragma unroll
        for (int dr = 0; dr < 4; ++dr) {
            int t = t0_[dr] + du; t = t < (T_ - 1) ? t : (T_ - 1);
            rbuf[du][dr] = p4[t * 16 + m];
        }

    float chk[4][4], endv[4][4];
#pragma unroll
    for (int dr = 0; dr < 4; ++dr)
#pragma unroll
        for (int q = 0; q < 4; ++q) { chk[dr][q] = 1.0f; endv[dr][q] = 1.0f; }

    for (int ub = 0; ub < Epad; ub += 4) {
#pragma unroll
        for (int du = 0; du < 4; ++du) {
            const int u = ub + du;
            float ep[4][4];
#pragma unroll
            for (int dr = 0; dr < 4; ++dr) {
                const float4 pv = rbuf[du][dr];
                ep[dr][0] = __expf(pv.x); ep[dr][1] = __expf(pv.y);
                ep[dr][2] = __expf(pv.z); ep[dr][3] = __expf(pv.w);
            }
            short8 a1, a2;
            __builtin_memcpy(&a1, zb + roff1, 16);
            __builtin_memcpy(&a2, zb + roff2, 16);
            const f32x4 zc = {0.f, 0.f, 0.f, 0.f};
            f32x4 acc0 = __builtin_amdgcn_mfma_f32_16x16x32_bf16(a1, B1[0], zc, 0, 0, 0);
            acc0 = __builtin_amdgcn_mfma_f32_16x16x32_bf16(a2, B2[0], acc0, 0, 0, 0);
            f32x4 acc1 = __builtin_amdgcn_mfma_f32_16x16x32_bf16(a1, B1[1], zc, 0, 0, 0);
            acc1 = __builtin_amdgcn_mfma_f32_16x16x32_bf16(a2, B2[1], acc1, 0, 0, 0);
            f32x4 acc2 = __builtin_amdgcn_mfma_f32_16x16x32_bf16(a1, B1[2], zc, 0, 0, 0);
            acc2 = __builtin_amdgcn_mfma_f32_16x16x32_bf16(a2, B2[2], acc2, 0, 0, 0);
            f32x4 acc3 = __builtin_amdgcn_mfma_f32_16x16x32_bf16(a1, B1[3], zc, 0, 0, 0);
            acc3 = __builtin_amdgcn_mfma_f32_16x16x32_bf16(a2, B2[3], acc3, 0, 0, 0);
            float cur[4][4];
#pragma unroll
            for (int dr = 0; dr < 4; ++dr) {
                cur[dr][0] = acc0[dr] * ep[dr][0];
                cur[dr][1] = acc1[dr] * ep[dr][1];
                cur[dr][2] = acc2[dr] * ep[dr][2];
                cur[dr][3] = acc3[dr] * ep[dr][3];
            }
            // capture events (wave-uniform branches)
            if (u == 7) {
#pragma unroll
                for (int dr = 0; dr < 4; ++dr)
#pragma unroll
                    for (int q = 0; q < 4; ++q) chk[dr][q] = cur[dr][q];
            }
            if (u == uendC0) {
#pragma unroll
                for (int q = 0; q < 4; ++q)
                    endv[0][q] = (g == 0) ? cur[0][q] : endv[0][q];
            }
            if (u == ufin) {
#pragma unroll
                for (int dr = 0; dr < 4; ++dr)
#pragma unroll
                    for (int q = 0; q < 4; ++q) {
                        const bool keep = (g == 0 && dr == 0) || (g == 3 && dr == 3);
                        endv[dr][q] = keep ? endv[dr][q] : cur[dr][q];
                    }
            }
            if (u == uend15) {
#pragma unroll
                for (int q = 0; q < 4; ++q)
                    endv[3][q] = (g == 3) ? cur[3][q] : endv[3][q];
            }
            // pack + swizzled write of next z
#pragma unroll
            for (int dr = 0; dr < 4; ++dr) {
                int2 wv;
                wv.x = pack2(cur[dr][0], cur[dr][1]);
                wv.y = pack2(cur[dr][2], cur[dr][3]);
                __builtin_memcpy(zb + woff[dr], &wv, 8);
            }
            // prefetch u+4
#pragma unroll
            for (int dr = 0; dr < 4; ++dr) {
                int t = t0_[dr] + u + 4; t = t < (T_ - 1) ? t : (T_ - 1);
                rbuf[du][dr] = p4[t * 16 + m];
            }
        }
    }

    // ---- combine: logZ = sum logs (telescoping) + 6*ln2*n ----
    float wE0 = __expf(A[(4 * m + 0) * NA_ + (N_ + 1)]);
    float wE1 = __expf(A[(4 * m + 1) * NA_ + (N_ + 1)]);
    float wE2 = __expf(A[(4 * m + 2) * NA_ + (N_ + 1)]);
    float wE3 = __expf(A[(4 * m + 3) * NA_ + (N_ + 1)]);
    float se[4], sk[4];
#pragma unroll
    for (int dr = 0; dr < 4; ++dr) {
        se[dr] = (endv[dr][0] + endv[dr][1]) + (endv[dr][2] + endv[dr][3]);
        sk[dr] = (chk[dr][0] + chk[dr][1]) + (chk[dr][2] + chk[dr][3]);
    }
    float swe = endv[3][0] * wE0 + endv[3][1] * wE1 + endv[3][2] * wE2 + endv[3][3] * wE3;
#pragma unroll
    for (int off = 1; off <= 8; off <<= 1) {
#pragma unroll
        for (int dr = 0; dr < 4; ++dr) {
            se[dr] += __shfl_xor(se[dr], off, 64);
            sk[dr] += __shfl_xor(sk[dr], off, 64);
        }
        swe += __shfl_xor(swe, off, 64);
    }
    float contrib = 0.f;
#pragma unroll
    for (int dr = 0; dr < 4; ++dr) {
        const int s = 4 * g + dr;
        contrib += (s <= 14) ? __logf(se[dr]) : 0.f;
        contrib -= (s >= 1) ? __logf(sk[dr]) : 0.f;
    }
    contrib += (g == 3) ? __logf(swe) * 0.0625f * 16.f : 0.f; // only dr=3 adds; per-lane once
    contrib += __shfl_xor(contrib, 16, 64);
    contrib += __shfl_xor(contrib, 32, 64);
    const float logZ = contrib + 6.0f * LN2 * (float)n;

    // ---- score ----
    float sc = 0.f;
    int carry = 0;
#pragma unroll
    for (int kk = 0; kk < 16; ++kk) {
        const int t = l + 64 * kk;
        const int yk = y[yb + t];
        int yp = __shfl_up(yk, 1, 64);
        if (l == 0) yp = carry;
        carry = __shfl(yk, 63, 64);
        const bool v = t < len;
        sc += v ? P[pbase + (long)t * N_ + yk] : 0.f;
        sc += (v && t >= 1) ? A[yp * NA_ + yk] : 0.f;
    }
#pragma unroll
    for (int off = 32; off >= 1; off >>= 1)
        sc += __shfl_xor(sc, off, 64);

    if (l == 0) {
        const int y0 = y[yb];
        const int yl = y[yb + len - 1];
        const float start = A[N_ * NA_ + y0];
        const float endA = A[yl * NA_ + (N_ + 1)];
        out[b] = logZ - (sc + start + endA);
    }
}

extern "C" void kernel_launch(void* const* d_in, const int* in_sizes, int n_in,
                              void* d_out, int out_size, void* d_ws, size_t ws_size,
                              hipStream_t stream) {
    const int* y = (const int*)d_in[0];
    const float* P = (const float*)d_in[1];
    const int* lens = (const int*)d_in[2];
    const float* A = (const float*)d_in[3];
    float* out = (float*)d_out;
    crf_mc16<<<dim3(B_), dim3(64), 0, stream>>>(y, P, lens, A, out);
}

// Round 11
// 43.328 us; speedup vs baseline: 2.4840x; 1.0492x over previous
//
#include <hip/hip_runtime.h>
#include <hip/hip_bf16.h>

#define B_ 512
#define T_ 1024
#define N_ 64
#define NA_ 66
#define K_ 64
#define BURN 5
#define LN2 0.69314718055994530942f

typedef __attribute__((ext_vector_type(8))) short short8;
typedef __attribute__((ext_vector_type(4))) float f32x4;

__device__ __forceinline__ unsigned short bf16_rne(float f) {
    unsigned u = __float_as_uint(f);
    u += 0x7fffu + ((u >> 16) & 1u);
    return (unsigned short)(u >> 16);
}
__device__ __forceinline__ int pack2(float a, float b) {
    __hip_bfloat162 h = __float22bfloat162_rn(make_float2(a, b)); // x -> low
    int r; __builtin_memcpy(&r, &h, 4); return r;
}

__global__ __launch_bounds__(256) void crf_mc64(
    const int* __restrict__ y,      // [B,T]
    const float* __restrict__ P,    // [B,T,N]
    const int* __restrict__ lens,   // [B]
    const float* __restrict__ A,    // [NA,NA]
    float* __restrict__ out)        // [B]
{
    const int b = blockIdx.x;
    const int tid = threadIdx.x;
    const int w = tid >> 6;         // wave: owns global chains 16w .. 16w+15
    const int l = tid & 63;
    const int g = l >> 4;           // k-group / C row-group
    const int m = l & 15;           // A-row (read side) / C col-pos
    const long pbase = (long)b * (T_ * N_);
    const int yb = b * T_;
    const int len = lens[b];        // in [512, 1024]
    const int n = len - 1;          // scan steps 511..1023
    const int L = (n + K_ - 1) / K_;            // owned steps per chain (8..16)
    const int Epad = ((L + BURN) + 3) & ~3;     // executed lockstep steps, padded

    // B-frags: B1[q][e] = W[8g+e][4m+q]*2^-6 (W = exp(Asub)); B2 rows 32+8g+e.
    short8 B1[4], B2[4];
#pragma unroll
    for (int q = 0; q < 4; ++q) {
        const int col = 4 * m + q;
#pragma unroll
        for (int e = 0; e < 8; ++e) {
            B1[q][e] = (short)bf16_rne(__expf(A[(8 * g + e) * NA_ + col]) * 0.015625f);
            B2[q][e] = (short)bf16_rne(__expf(A[(32 + 8 * g + e) * NA_ + col]) * 0.015625f);
        }
    }

    __shared__ __align__(16) unsigned char zb[4][2048];  // per-wave z[16][64] bf16
    __shared__ float gsh[4];
    __shared__ float psh[4];
    unsigned char* zbw = zb[w];

    // LDS: granule (8 states = 16 B) XOR-swizzled by (chain&7)  [r10-proven]
    const int roff1 = m * 128 + 16 * (g ^ (m & 7));
    const int roff2 = m * 128 + 16 * ((g + 4) ^ (m & 7));
    int woff[4], t0_[4], ue[4];
#pragma unroll
    for (int dr = 0; dr < 4; ++dr) {
        const int i = 4 * g + dr;           // local chain (write/scale side)
        const int c = 16 * w + i;           // global chain
        woff[dr] = i * 128 + 16 * ((m >> 1) ^ (i & 7)) + 8 * (m & 1);
        t0_[dr] = c ? (c * L - (BURN - 1)) : 1;
        const int tend = min((c + 1) * L, n);
        ue[dr] = (c == 0) ? (L - 1)
               : ((c * L >= n) ? (BURN - 1) : (BURN - 1 + tend - c * L));
    }

    const float4* __restrict__ p4 = (const float4*)(P + pbase);

    // init z: global chain 0 = exp(A[START,:]+P[0,:]) exact; others uniform 1
    {
        const float4 p0 = p4[m];
        const float v0 = __expf(A[N_ * NA_ + 4 * m + 0] + p0.x);
        const float v1 = __expf(A[N_ * NA_ + 4 * m + 1] + p0.y);
        const float v2 = __expf(A[N_ * NA_ + 4 * m + 2] + p0.z);
        const float v3 = __expf(A[N_ * NA_ + 4 * m + 3] + p0.w);
#pragma unroll
        for (int dr = 0; dr < 4; ++dr) {
            const bool c0 = (w == 0 && g == 0 && dr == 0);
            int2 wv;
            wv.x = pack2(c0 ? v0 : 1.0f, c0 ? v1 : 1.0f);
            wv.y = pack2(c0 ? v2 : 1.0f, c0 ? v3 : 1.0f);
            __builtin_memcpy(zbw + woff[dr], &wv, 8);
        }
    }

    float4 rbuf[4][4];                  // prefetch ring [slot][dr], distance 4
#pragma unroll
    for (int du = 0; du < 4; ++du)
#pragma unroll
        for (int dr = 0; dr < 4; ++dr) {
            int t = t0_[dr] + du; t = t < (T_ - 1) ? t : (T_ - 1);
            rbuf[du][dr] = p4[t * 16 + m];
        }

    float chk[4][4], endv[4][4];
#pragma unroll
    for (int dr = 0; dr < 4; ++dr)
#pragma unroll
        for (int q = 0; q < 4; ++q) { chk[dr][q] = 1.0f; endv[dr][q] = 1.0f; }

    for (int ub = 0; ub < Epad; ub += 4) {
#pragma unroll
        for (int du = 0; du < 4; ++du) {
            const int u = ub + du;
            float ep[4][4];
#pragma unroll
            for (int dr = 0; dr < 4; ++dr) {
                const float4 pv = rbuf[du][dr];
                ep[dr][0] = __expf(pv.x); ep[dr][1] = __expf(pv.y);
                ep[dr][2] = __expf(pv.z); ep[dr][3] = __expf(pv.w);
            }
            short8 a1, a2;
            __builtin_memcpy(&a1, zbw + roff1, 16);
            __builtin_memcpy(&a2, zbw + roff2, 16);
            const f32x4 zc = {0.f, 0.f, 0.f, 0.f};
            f32x4 acc0 = __builtin_amdgcn_mfma_f32_16x16x32_bf16(a1, B1[0], zc, 0, 0, 0);
            acc0 = __builtin_amdgcn_mfma_f32_16x16x32_bf16(a2, B2[0], acc0, 0, 0, 0);
            f32x4 acc1 = __builtin_amdgcn_mfma_f32_16x16x32_bf16(a1, B1[1], zc, 0, 0, 0);
            acc1 = __builtin_amdgcn_mfma_f32_16x16x32_bf16(a2, B2[1], acc1, 0, 0, 0);
            f32x4 acc2 = __builtin_amdgcn_mfma_f32_16x16x32_bf16(a1, B1[2], zc, 0, 0, 0);
            acc2 = __builtin_amdgcn_mfma_f32_16x16x32_bf16(a2, B2[2], acc2, 0, 0, 0);
            f32x4 acc3 = __builtin_amdgcn_mfma_f32_16x16x32_bf16(a1, B1[3], zc, 0, 0, 0);
            acc3 = __builtin_amdgcn_mfma_f32_16x16x32_bf16(a2, B2[3], acc3, 0, 0, 0);
            float cur[4][4];
#pragma unroll
            for (int dr = 0; dr < 4; ++dr) {
                cur[dr][0] = acc0[dr] * ep[dr][0];
                cur[dr][1] = acc1[dr] * ep[dr][1];
                cur[dr][2] = acc2[dr] * ep[dr][2];
                cur[dr][3] = acc3[dr] * ep[dr][3];
            }
            if (u == BURN - 1) {                 // uniform: checkpoint capture
#pragma unroll
                for (int dr = 0; dr < 4; ++dr)
#pragma unroll
                    for (int q = 0; q < 4; ++q) chk[dr][q] = cur[dr][q];
            }
#pragma unroll
            for (int dr = 0; dr < 4; ++dr) {     // per-chain end capture (cndmask)
                const bool hit = (u == ue[dr]);
#pragma unroll
                for (int q = 0; q < 4; ++q)
                    endv[dr][q] = hit ? cur[dr][q] : endv[dr][q];
            }
#pragma unroll
            for (int dr = 0; dr < 4; ++dr) {     // pack + swizzled write of next z
                int2 wv;
                wv.x = pack2(cur[dr][0], cur[dr][1]);
                wv.y = pack2(cur[dr][2], cur[dr][3]);
                __builtin_memcpy(zbw + woff[dr], &wv, 8);
            }
#pragma unroll
            for (int dr = 0; dr < 4; ++dr) {     // prefetch u+4
                int t = t0_[dr] + u + 4; t = t < (T_ - 1) ? t : (T_ - 1);
                rbuf[du][dr] = p4[t * 16 + m];
            }
        }
    }

    // ---- per-wave combine: telescoping log-gains ----
    const float wE0 = __expf(A[(4 * m + 0) * NA_ + (N_ + 1)]);
    const float wE1 = __expf(A[(4 * m + 1) * NA_ + (N_ + 1)]);
    const float wE2 = __expf(A[(4 * m + 2) * NA_ + (N_ + 1)]);
    const float wE3 = __expf(A[(4 * m + 3) * NA_ + (N_ + 1)]);
    float se[4], sk[4], swe[4];
#pragma unroll
    for (int dr = 0; dr < 4; ++dr) {
        se[dr] = (endv[dr][0] + endv[dr][1]) + (endv[dr][2] + endv[dr][3]);
        sk[dr] = (chk[dr][0] + chk[dr][1]) + (chk[dr][2] + chk[dr][3]);
        swe[dr] = endv[dr][0] * wE0 + endv[dr][1] * wE1
                + endv[dr][2] * wE2 + endv[dr][3] * wE3;
    }
#pragma unroll
    for (int off = 1; off <= 8; off <<= 1) {
#pragma unroll
        for (int dr = 0; dr < 4; ++dr) {
            se[dr]  += __shfl_xor(se[dr],  off, 64);
            sk[dr]  += __shfl_xor(sk[dr],  off, 64);
            swe[dr] += __shfl_xor(swe[dr], off, 64);
        }
    }
    float contrib = 0.f;
#pragma unroll
    for (int dr = 0; dr < 4; ++dr) {
        const int c = 16 * w + 4 * g + dr;
        const bool isfin = (c * L < n) && (min((c + 1) * L, n) == n);
        contrib += isfin ? __logf(swe[dr]) : __logf(se[dr]);
        contrib -= (c >= 1) ? __logf(sk[dr]) : 0.f;
    }
    contrib += __shfl_xor(contrib, 16, 64);   // sum the 4 g-groups (1 lane each)
    contrib += __shfl_xor(contrib, 32, 64);
    if (l == 0) gsh[w] = contrib;

    // ---- score partials: 256 threads x 4 timesteps ----
    float sc = 0.f;
#pragma unroll
    for (int kk = 0; kk < 4; ++kk) {
        const int t = tid + 256 * kk;         // 0..1023
        const int yt = y[yb + t];
        const bool v = t < len;
        sc += v ? P[pbase + (long)t * N_ + yt] : 0.f;
        sc += (v && t >= 1) ? A[y[yb + t - 1] * NA_ + yt] : 0.f;
    }
#pragma unroll
    for (int off = 32; off >= 1; off >>= 1)
        sc += __shfl_xor(sc, off, 64);
    if (l == 0) psh[w] = sc;
    __syncthreads();

    if (tid == 0) {
        const float logZ = gsh[0] + gsh[1] + gsh[2] + gsh[3]
                         + 6.0f * LN2 * (float)n;
        const float score = psh[0] + psh[1] + psh[2] + psh[3]
                          + A[N_ * NA_ + y[yb]]
                          + A[y[yb + len - 1] * NA_ + (N_ + 1)];
        out[b] = logZ - score;
    }
}

extern "C" void kernel_launch(void* const* d_in, const int* in_sizes, int n_in,
                              void* d_out, int out_size, void* d_ws, size_t ws_size,
                              hipStream_t stream) {
    const int* y = (const int*)d_in[0];
    const float* P = (const float*)d_in[1];
    const int* lens = (const int*)d_in[2];
    const float* A = (const float*)d_in[3];
    float* out = (float*)d_out;
    crf_mc64<<<dim3(B_), dim3(256), 0, stream>>>(y, P, lens, A, out);
}